// Round 7
// baseline (146.949 us; speedup 1.0000x reference)
//
#include <hip/hip_runtime.h>
#include <math.h>

// Fused soft-argmax centroid over [B,K,128,128] fp32, two inputs.
// 2048 blocks x 256 threads. Forced memory-level parallelism:
// sched_barrier(0) fences pin two 8-deep load clusters so the amdgpu
// scheduler cannot sink loads next to uses (rounds 4/6 compiled to
// VGPR=32, ~4-deep, 3.1 TB/s). Target: 8-16 loads in flight per wave.

#define HM_H 128
#define HM_W 128

__global__ __launch_bounds__(256, 4) void centroid_mlp(
    const float* __restrict__ hm0,
    const float* __restrict__ hm1,
    float* __restrict__ out,
    int BK)
{
    const int u  = blockIdx.x;                 // 0 .. 2*BK-1
    const int bk = (u >= BK) ? (u - BK) : u;
    const float4* __restrict__ p =
        (const float4*)(((u >= BK) ? hm1 : hm0) + (size_t)bk * (HM_H * HM_W));
    const int t = threadIdx.x;

    const float colb = (float)((t << 2) & (HM_W - 1)); // column of lane's 4-group
    const float rowb = (float)(t >> 5);                // row of load m = rowb + 8m

    // ---- cluster 1: issue loads m = 0..7 ----
    const float4 v0 = p[t];
    const float4 v1 = p[t +  256];
    const float4 v2 = p[t +  512];
    const float4 v3 = p[t +  768];
    const float4 v4 = p[t + 1024];
    const float4 v5 = p[t + 1280];
    const float4 v6 = p[t + 1536];
    const float4 v7 = p[t + 1792];
    __builtin_amdgcn_sched_barrier(0);   // loads may not sink below this point

    // ---- cluster 2 issue (m = 8..15) overlapped with cluster-1 consume ----
    const float4 v8  = p[t + 2048];
    const float4 v9  = p[t + 2304];
    const float4 v10 = p[t + 2560];
    const float4 v11 = p[t + 2816];
    const float4 v12 = p[t + 3072];
    const float4 v13 = p[t + 3328];
    const float4 v14 = p[t + 3584];
    const float4 v15 = p[t + 3840];

#define SV(V) ((V).x + (V).y + (V).z + (V).w)
#define YZ(V) ((V).y + 2.0f * (V).z + 3.0f * (V).w)

    const float sv0 = SV(v0), sv1 = SV(v1), sv2 = SV(v2), sv3 = SV(v3);
    const float sv4 = SV(v4), sv5 = SV(v5), sv6 = SV(v6), sv7 = SV(v7);
    const float s1  = ((sv0 + sv1) + (sv2 + sv3)) + ((sv4 + sv5) + (sv6 + sv7));
    const float ms1 = (sv1 + 2.0f * sv2) + (3.0f * sv3 + 4.0f * sv4)
                    + (5.0f * sv5 + 6.0f * sv6) + 7.0f * sv7;
    const float yz1 = ((YZ(v0) + YZ(v1)) + (YZ(v2) + YZ(v3)))
                    + ((YZ(v4) + YZ(v5)) + (YZ(v6) + YZ(v7)));
    __builtin_amdgcn_sched_barrier(0);   // cluster-2 loads stay above (8+ in flight)

    // ---- consume cluster 2 ----
    const float sv8  = SV(v8),  sv9  = SV(v9),  sv10 = SV(v10), sv11 = SV(v11);
    const float sv12 = SV(v12), sv13 = SV(v13), sv14 = SV(v14), sv15 = SV(v15);
    const float s2  = ((sv8 + sv9) + (sv10 + sv11)) + ((sv12 + sv13) + (sv14 + sv15));
    const float ms2 = 8.0f * s2
                    + (sv9 + 2.0f * sv10) + (3.0f * sv11 + 4.0f * sv12)
                    + (5.0f * sv13 + 6.0f * sv14) + 7.0f * sv15;
    const float yz2 = ((YZ(v8)  + YZ(v9))  + (YZ(v10) + YZ(v11)))
                    + ((YZ(v12) + YZ(v13)) + (YZ(v14) + YZ(v15)));
#undef SV
#undef YZ

    const float s = s1 + s2;
    float sx = colb * s + (yz1 + yz2);
    float sy = rowb * s + 8.0f * (ms1 + ms2);

    // ---- wave (64-lane) butterfly reduce ----
    float ss = s;
#pragma unroll
    for (int off = 32; off > 0; off >>= 1) {
        ss += __shfl_down(ss, off, 64);
        sx += __shfl_down(sx, off, 64);
        sy += __shfl_down(sy, off, 64);
    }

    __shared__ float ls[4], lx[4], ly[4];
    const int wid  = t >> 6;
    const int lane = t & 63;
    if (lane == 0) { ls[wid] = ss; lx[wid] = sx; ly[wid] = sy; }
    __syncthreads();

    if (t == 0) {
        const float S = ls[0] + ls[1] + ls[2] + ls[3];
        const float X = lx[0] + lx[1] + lx[2] + lx[3];
        const float Y = ly[0] + ly[1] + ly[2] + ly[3];
        // out = [keypoint (BK*2) | tf_keypoint (BK*2)]
        out[u * 2 + 0] = rintf(X / S);   // round-half-to-even == jnp.round
        out[u * 2 + 1] = rintf(Y / S);
    }
}

extern "C" void kernel_launch(void* const* d_in, const int* in_sizes, int n_in,
                              void* d_out, int out_size, void* d_ws, size_t ws_size,
                              hipStream_t stream) {
    const float* hm0 = (const float*)d_in[0];
    const float* hm1 = (const float*)d_in[1];
    float* out = (float*)d_out;

    const int BK     = out_size / 4;   // B*K
    const int nunits = 2 * BK;         // 2048 blocks

    centroid_mlp<<<nunits, 256, 0, stream>>>(hm0, hm1, out, BK);
}

// Round 8
// 136.684 us; speedup vs baseline: 1.0751x; 1.0751x over previous
//
#include <hip/hip_runtime.h>
#include <math.h>

// Fused soft-argmax centroid over [B,K,128,128] fp32, two inputs.
// Round-1 structure (2048 blocks x 256 threads, 16 float4/thread) with ONE
// change: nontemporal loads (nt flag -> streaming, no cache allocate).
// Tests the cache-allocation-overhead hypothesis for the ~3.1 TB/s read cap.

#define HM_H 128
#define HM_W 128

typedef float vf4 __attribute__((ext_vector_type(4)));

__global__ __launch_bounds__(256) void centroid_nt(
    const float* __restrict__ hm0,
    const float* __restrict__ hm1,
    float* __restrict__ out,
    int BK)
{
    const int u  = blockIdx.x;                 // 0 .. 2*BK-1
    const int bk = (u >= BK) ? (u - BK) : u;
    const vf4* __restrict__ p =
        (const vf4*)(((u >= BK) ? hm1 : hm0) + (size_t)bk * (HM_H * HM_W));
    const int t = threadIdx.x;

    const float colb = (float)((t << 2) & (HM_W - 1)); // column of lane's 4-group
    const float rowb = (float)(t >> 5);                // row of chunk m = rowb + 8m

    float s = 0.0f, sx = 0.0f, sy = 0.0f;

#pragma unroll
    for (int m = 0; m < 16; ++m) {
        const vf4 v = __builtin_nontemporal_load(&p[t + m * 256]);
        const float sv = (v[0] + v[1]) + (v[2] + v[3]);
        s  += sv;
        sx += (v[1] + 2.0f * v[2]) + 3.0f * v[3];
        sy += (float)(8 * m) * sv;             // global row = rowb + 8m
    }
    sx += colb * s;
    sy += rowb * s;

    // ---- wave (64-lane) butterfly reduce ----
    float ss = s;
#pragma unroll
    for (int off = 32; off > 0; off >>= 1) {
        ss += __shfl_down(ss, off, 64);
        sx += __shfl_down(sx, off, 64);
        sy += __shfl_down(sy, off, 64);
    }

    __shared__ float ls[4], lx[4], ly[4];
    const int wid  = t >> 6;
    const int lane = t & 63;
    if (lane == 0) { ls[wid] = ss; lx[wid] = sx; ly[wid] = sy; }
    __syncthreads();

    if (t == 0) {
        const float S = ls[0] + ls[1] + ls[2] + ls[3];
        const float X = lx[0] + lx[1] + lx[2] + lx[3];
        const float Y = ly[0] + ly[1] + ly[2] + ly[3];
        // out = [keypoint (BK*2) | tf_keypoint (BK*2)]
        out[u * 2 + 0] = rintf(X / S);   // round-half-to-even == jnp.round
        out[u * 2 + 1] = rintf(Y / S);
    }
}

extern "C" void kernel_launch(void* const* d_in, const int* in_sizes, int n_in,
                              void* d_out, int out_size, void* d_ws, size_t ws_size,
                              hipStream_t stream) {
    const float* hm0 = (const float*)d_in[0];
    const float* hm1 = (const float*)d_in[1];
    float* out = (float*)d_out;

    const int BK     = out_size / 4;   // B*K
    const int nunits = 2 * BK;         // 2048 blocks

    centroid_nt<<<nunits, 256, 0, stream>>>(hm0, hm1, out, BK);
}